// Round 2
// baseline (132.429 us; speedup 1.0000x reference)
//
#include <hip/hip_runtime.h>

#define T_SZ   16384
#define CIN    8
#define COUT   8
#define NPART  16
#define PART_T 1024
#define NCHUNK 32     // chunks per part (old path)
#define CHT    32     // timesteps per chunk (old path)
#define BAR_OFFSET_BYTES (1 << 17)   // barrier counter location in ws (past root area)

// ---- fused-512 geometry: 8 parts x 2048, 32 chunks x 64 steps, 512 blocks ----
#define NPART2  8
#define PART2_T 2048
#define NCHK2   32
#define CHT2    64
#define BVS     516            // floats per chunk block in LDS (64*8 + 4 pad -> <=2-way banks)
#define GRID2   (64 * NPART2)  // 512 blocks = 2 per CU (LDS-limited), all co-resident

struct V3 { float x, y, z; };
__device__ __forceinline__ V3 mkv3(float a, float b, float c) { V3 r; r.x=a; r.y=b; r.z=c; return r; }
__device__ __forceinline__ V3 vadd3(V3 a, V3 b) { return mkv3(a.x+b.x, a.y+b.y, a.z+b.z); }
__device__ __forceinline__ V3 vfma3(V3 acc, float s, V3 w) {
  return mkv3(fmaf(s, w.x, acc.x), fmaf(s, w.y, acc.y), fmaf(s, w.z, acc.z));
}
// A rows: (a0,a1,a2),(0,a1,a2),(0,0,a2)
__device__ __forceinline__ V3 aappf(float a0, float a1, float a2, V3 v) {
  float t2 = a2 * v.z;
  float t1 = fmaf(a1, v.y, t2);
  return mkv3(fmaf(a0, v.x, t1), t1, t2);
}
// combine: E(left|right) = A*E_left + E_right
__device__ __forceinline__ V3 comb(float a0, float a1, float a2, V3 l, V3 r) {
  return vadd3(aappf(a0, a1, a2, l), r);
}

struct Row { float4 lo, hi; };
__device__ __forceinline__ Row ldrow(const float* p) {
  Row r; r.lo = *(const float4*)p; r.hi = *(const float4*)(p + 4); return r;
}
__device__ __forceinline__ Row zrow() { Row r; r.lo = make_float4(0.f,0.f,0.f,0.f); r.hi = r.lo; return r; }
__device__ __forceinline__ float rdot(const Row& r, const float* w) {
  float s = r.lo.x * w[0];
  s = fmaf(r.lo.y, w[1], s); s = fmaf(r.lo.z, w[2], s); s = fmaf(r.lo.w, w[3], s);
  s = fmaf(r.hi.x, w[4], s); s = fmaf(r.hi.y, w[5], s); s = fmaf(r.hi.z, w[6], s);
  s = fmaf(r.hi.w, w[7], s);
  return s;
}

// ======================= OLD (fallback) PATH — verbatim =======================
struct Pre {
  float bv[CHT];
  V3 e0, e1, E5;
  float a0, a1, a2;
  int o, c, p, b, t0;
};

__device__ __forceinline__ void preamble(
    Pre& P, const float* __restrict__ u, const float* __restrict__ x0,
    const float* __restrict__ ac, const float* __restrict__ bc)
{
  const int j = threadIdx.x;
  P.o = j & 7;  P.c = j >> 3;
  P.p = blockIdx.x & 15;  P.b = blockIdx.x >> 4;
  const int o = P.o;
  P.a0 = ac[0*COUT + o];  P.a1 = ac[1*COUT + o];  P.a2 = ac[2*COUT + o];
  const float a0 = P.a0, a1 = P.a1, a2 = P.a2;

  float w0[8], w1[8], w2[8], w3[8];
#pragma unroll
  for (int i = 0; i < 8; ++i) {
    w0[i] = bc[(0*CIN + i)*COUT + o];
    w1[i] = bc[(1*CIN + i)*COUT + o];
    w2[i] = bc[(2*CIN + i)*COUT + o];
    w3[i] = bc[(3*CIN + i)*COUT + o];
  }

  const float* ub = u + (size_t)P.b * T_SZ * CIN;
  P.t0 = P.p * PART_T + P.c * CHT;
  const int t0 = P.t0;

  {
    Row ra, rb, rc;
    if (t0 == 0) { ra = zrow(); rb = zrow(); rc = zrow(); }
    else {
      ra = ldrow(ub + (size_t)(t0 - 3) * CIN);
      rb = ldrow(ub + (size_t)(t0 - 2) * CIN);
      rc = ldrow(ub + (size_t)(t0 - 1) * CIN);
    }
#pragma unroll
    for (int r = 0; r < CHT; ++r) {
      Row rd = ldrow(ub + (size_t)(t0 + r) * CIN);
      P.bv[r] = rdot(ra, w0) + rdot(rb, w1) + rdot(rc, w2) + rdot(rd, w3);
      ra = rb; rb = rc; rc = rd;
    }
  }

  P.e0 = mkv3(0,0,0);  P.e1 = mkv3(0,0,0);
  if (t0 == 0) {
    float x00 = x0[((size_t)P.b*3 + 0)*COUT + o];
    float x01 = x0[((size_t)P.b*3 + 1)*COUT + o];
    float x02 = x0[((size_t)P.b*3 + 2)*COUT + o];
    float first = P.bv[0] + a2*x00 + a1*x01 + a0*x02;
    P.e0 = mkv3(first, x02, x01);
    P.e1 = mkv3(P.bv[1], P.bv[1], x02);
  }

  V3 gt[6];
  gt[0] = mkv3(1.f,1.f,1.f);
#pragma unroll
  for (int k = 1; k <= 5; ++k) gt[k] = aappf(a0,a1,a2, gt[k-1]);
  V3 acc;
  if (t0 == 0) {
    V3 q0 = P.e0, q1 = P.e1;
#pragma unroll
    for (int k = 0; k < 5; ++k) q0 = aappf(a0,a1,a2, q0);
#pragma unroll
    for (int k = 0; k < 4; ++k) q1 = aappf(a0,a1,a2, q1);
    acc = vadd3(q0, q1);
#pragma unroll
    for (int r = 2; r < CHT; ++r) acc = vfma3(acc, P.bv[r], gt[5 - __popc(r)]);
  } else {
    acc = mkv3(0,0,0);
#pragma unroll
    for (int r = 0; r < CHT; ++r) acc = vfma3(acc, P.bv[r], gt[5 - __popc(r)]);
  }
  P.E5 = acc;
}

__global__ __launch_bounds__(256) void ldtf_p1(
    const float* __restrict__ u, const float* __restrict__ x0,
    const float* __restrict__ ac, const float* __restrict__ bc,
    float* __restrict__ ws)
{
  __shared__ V3 s_E5[NCHUNK*8];
  __shared__ V3 s_tr[30*8];

  Pre P;
  preamble(P, u, x0, ac, bc);
  const int j = threadIdx.x, o = P.o;
  const float a0 = P.a0, a1 = P.a1, a2 = P.a2;

  s_E5[P.c*8 + o] = P.E5;
  __syncthreads();
  if (j < 128) { int i = j >> 3; s_tr[i*8+o]      = comb(a0,a1,a2, s_E5[(2*i)*8+o],    s_E5[(2*i+1)*8+o]); }
  __syncthreads();
  if (j < 64)  { int i = j >> 3; s_tr[(16+i)*8+o] = comb(a0,a1,a2, s_tr[(2*i)*8+o],    s_tr[(2*i+1)*8+o]); }
  __syncthreads();
  if (j < 32)  { int i = j >> 3; s_tr[(24+i)*8+o] = comb(a0,a1,a2, s_tr[(16+2*i)*8+o], s_tr[(16+2*i+1)*8+o]); }
  __syncthreads();
  if (j < 16)  { int i = j >> 3; s_tr[(28+i)*8+o] = comb(a0,a1,a2, s_tr[(24+2*i)*8+o], s_tr[(24+2*i+1)*8+o]); }
  __syncthreads();
  if (j < 8) {
    V3 rt = comb(a0,a1,a2, s_tr[28*8+o], s_tr[29*8+o]);
    float* wp = ws + ((size_t)(P.b*NPART + P.p)*8 + o)*3;
    wp[0] = rt.x; wp[1] = rt.y; wp[2] = rt.z;
  }
}

#define POOL_FLOATS 8448

__global__ __launch_bounds__(256) void ldtf_p2(
    const float* __restrict__ u, const float* __restrict__ x0,
    const float* __restrict__ ac, const float* __restrict__ bc,
    float* __restrict__ out, const float* __restrict__ ws)
{
  __shared__ __align__(16) float s_pool[POOL_FLOATS];
  V3* s_E5 = (V3*)s_pool;
  V3* s_tr = (V3*)s_pool + 256;
  V3* s_mt = (V3*)s_pool + 496;
  float* s_out = s_pool;

  Pre P;
  preamble(P, u, x0, ac, bc);
  const int j = threadIdx.x, o = P.o, c = P.c, p = P.p, b = P.b;
  const float a0 = P.a0, a1 = P.a1, a2 = P.a2;

  s_E5[c*8 + o] = P.E5;
  if (j < 128) {
    int c2 = j >> 3;
    const float* wp = ws + ((size_t)(b*NPART + c2)*8 + o)*3;
    s_mt[c2*8+o] = mkv3(wp[0], wp[1], wp[2]);
  }
  __syncthreads();

  if (j < 128) { int i = j >> 3; s_tr[i*8+o]      = comb(a0,a1,a2, s_E5[(2*i)*8+o],    s_E5[(2*i+1)*8+o]); }
  else         { int i = (j-128) >> 3; if (i < 8) s_mt[(16+i)*8+o] = comb(a0,a1,a2, s_mt[(2*i)*8+o], s_mt[(2*i+1)*8+o]); }
  __syncthreads();
  if (j < 64)  { int i = j >> 3; s_tr[(16+i)*8+o] = comb(a0,a1,a2, s_tr[(2*i)*8+o],    s_tr[(2*i+1)*8+o]); }
  else if (j >= 128) { int i = (j-128) >> 3; if (i < 4) s_mt[(24+i)*8+o] = comb(a0,a1,a2, s_mt[(16+2*i)*8+o], s_mt[(16+2*i+1)*8+o]); }
  __syncthreads();
  if (j < 32)  { int i = j >> 3; s_tr[(24+i)*8+o] = comb(a0,a1,a2, s_tr[(16+2*i)*8+o], s_tr[(16+2*i+1)*8+o]); }
  else if (j >= 128) { int i = (j-128) >> 3; if (i < 2) s_mt[(28+i)*8+o] = comb(a0,a1,a2, s_mt[(24+2*i)*8+o], s_mt[(24+2*i+1)*8+o]); }
  __syncthreads();
  if (j < 16)  { int i = j >> 3; s_tr[(28+i)*8+o] = comb(a0,a1,a2, s_tr[(24+2*i)*8+o], s_tr[(24+2*i+1)*8+o]); }
  __syncthreads();

  V3 sig = mkv3(0,0,0);
  if ((p >> 3) & 1) sig = comb(a0,a1,a2, sig, s_mt[(28 + (p>>3) - 1)*8 + o]);
  if ((p >> 2) & 1) sig = comb(a0,a1,a2, sig, s_mt[(24 + (p>>2) - 1)*8 + o]);
  if ((p >> 1) & 1) sig = comb(a0,a1,a2, sig, s_mt[(16 + (p>>1) - 1)*8 + o]);
  if (p & 1)        sig = comb(a0,a1,a2, sig, s_mt[(p - 1)*8 + o]);
  if ((c >> 4) & 1) sig = comb(a0,a1,a2, sig, s_tr[(28 + (c>>4) - 1)*8 + o]);
  if ((c >> 3) & 1) sig = comb(a0,a1,a2, sig, s_tr[(24 + (c>>3) - 1)*8 + o]);
  if ((c >> 2) & 1) sig = comb(a0,a1,a2, sig, s_tr[(16 + (c>>2) - 1)*8 + o]);
  if ((c >> 1) & 1) sig = comb(a0,a1,a2, sig, s_tr[((c>>1) - 1)*8 + o]);
  if (c & 1)        sig = comb(a0,a1,a2, sig, s_E5[(c - 1)*8 + o]);

  V3 tau;
  {
    int q = p + 1;
    if (q == 16) tau = comb(a0,a1,a2, s_mt[28*8+o], s_mt[29*8+o]);
    else {
      tau = mkv3(0,0,0);
      if ((q >> 3) & 1) tau = comb(a0,a1,a2, tau, s_mt[(28 + (q>>3) - 1)*8 + o]);
      if ((q >> 2) & 1) tau = comb(a0,a1,a2, tau, s_mt[(24 + (q>>2) - 1)*8 + o]);
      if ((q >> 1) & 1) tau = comb(a0,a1,a2, tau, s_mt[(16 + (q>>1) - 1)*8 + o]);
      if (q & 1)        tau = comb(a0,a1,a2, tau, s_mt[(q - 1)*8 + o]);
    }
  }
  __syncthreads();

  if (c >= 1) s_out[(c - 1)*264 + 31*8 + o] = sig.x;
  if (c == NCHUNK - 1) s_out[31*264 + 31*8 + o] = tau.x;

  {
    V3 st[5];
#pragma unroll
    for (int r = 0; r < CHT - 1; ++r) {
      V3 v = mkv3(P.bv[r], P.bv[r], P.bv[r]);
      if (P.t0 == 0) { if (r == 0) v = P.e0; if (r == 1) v = P.e1; }
      if (r & 1)          v = comb(a0,a1,a2, st[0], v);
      if ((r & 3) == 3)   v = comb(a0,a1,a2, st[1], v);
      if ((r & 7) == 7)   v = comb(a0,a1,a2, st[2], v);
      if ((r & 15) == 15) v = comb(a0,a1,a2, st[3], v);
      const int lvl = (r & 1) ? (((r & 3) == 3) ? (((r & 7) == 7) ? (((r & 15) == 15) ? 4 : 3) : 2) : 1) : 0;
      st[lvl] = v;
      const int i = r + 1;
      V3 acc = sig;
      if (i & 16) acc = comb(a0,a1,a2, acc, st[4]);
      if (i & 8)  acc = comb(a0,a1,a2, acc, st[3]);
      if (i & 4)  acc = comb(a0,a1,a2, acc, st[2]);
      if (i & 2)  acc = comb(a0,a1,a2, acc, st[1]);
      if (i & 1)  acc = comb(a0,a1,a2, acc, st[0]);
      s_out[c*264 + r*8 + o] = acc.x;
    }
  }
  __syncthreads();

  float* og = out + ((size_t)b * T_SZ + (size_t)p * PART_T) * COUT;
#pragma unroll
  for (int it = 0; it < 8; ++it) {
    int f = (it * 256 + j) * 4;
    float4 v = *(const float4*)&s_out[(f >> 8) * 264 + (f & 255)];
    *(float4*)&og[f] = v;
  }
}

// ======================= FUSED 512-BLOCK SINGLE-PASS =======================
// 8 parts x 2048 steps; 256 threads = 32 chunks x 8 outs; CHT2=64 steps/thread.
// bv lives in LDS (stride 516 floats -> <=2-way bank aliasing, free).
// Math is node-for-node identical to the old 16x32x32 decomposition (same
// balanced dyadic-tree nodes, same MSB->LSB Fenwick folds, leaf weight
// A^(6-popc6) == A^(5-popc5) + one tree level).
// LDS: 66048 + 3072 + 2880 + 1440 = 73440 B -> exactly 2 blocks/CU -> all 512
// blocks co-resident -> device-scope spin barrier is deadlock-free (host-gated).
__global__ __launch_bounds__(256, 2) void ldtf_fused512(
    const float* __restrict__ u, const float* __restrict__ x0,
    const float* __restrict__ ac, const float* __restrict__ bc,
    float* __restrict__ out, float* __restrict__ ws,
    unsigned int* __restrict__ bar)
{
  __shared__ __align__(16) float s_bv[NCHK2 * BVS];   // 16512 floats
  __shared__ V3 s_lf[NCHK2 * 8];                      // chunk leaves (E6)
  __shared__ V3 s_tr[30 * 8];                         // in-part tree l1..l4
  __shared__ V3 s_mt[15 * 8];                         // mini-tree: 8 leaves, 4 l1, 2 l2, 1 root

  const int j = threadIdx.x;
  const int o = j & 7, c = j >> 3;
  const int p = blockIdx.x & 7, b = blockIdx.x >> 3;

  const float a0 = ac[0*COUT + o], a1 = ac[1*COUT + o], a2 = ac[2*COUT + o];

  float w0[8], w1[8], w2[8], w3[8];
#pragma unroll
  for (int i = 0; i < 8; ++i) {
    w0[i] = bc[(0*CIN + i)*COUT + o];
    w1[i] = bc[(1*CIN + i)*COUT + o];
    w2[i] = bc[(2*CIN + i)*COUT + o];
    w3[i] = bc[(3*CIN + i)*COUT + o];
  }

  const float* ub = u + (size_t)b * T_SZ * CIN;
  const int t0 = p * PART2_T + c * CHT2;
  const bool z0 = (t0 == 0);

  V3 gt[7];
  gt[0] = mkv3(1.f,1.f,1.f);
#pragma unroll
  for (int k = 1; k <= 6; ++k) gt[k] = aappf(a0,a1,a2, gt[k-1]);

  // ---- FIR: 64 steps, bv -> LDS, leaf fold E6 inline ----
  float bv0r = 0.f, bv1r = 0.f;
  V3 accE = mkv3(0,0,0);
  float* bvp = &s_bv[c * BVS + o];
  {
    Row ra, rb, rc;
    if (z0) { ra = zrow(); rb = zrow(); rc = zrow(); }
    else {
      ra = ldrow(ub + (size_t)(t0 - 3) * CIN);
      rb = ldrow(ub + (size_t)(t0 - 2) * CIN);
      rc = ldrow(ub + (size_t)(t0 - 1) * CIN);
    }
#pragma unroll
    for (int r = 0; r < CHT2; ++r) {
      Row rd = ldrow(ub + (size_t)(t0 + r) * CIN);
      float bvr = rdot(ra, w0) + rdot(rb, w1) + rdot(rc, w2) + rdot(rd, w3);
      bvp[r*8] = bvr;
      if (r == 0) bv0r = bvr;
      if (r == 1) bv1r = bvr;
      if (!(z0 && r < 2)) accE = vfma3(accE, bvr, gt[6 - __popc(r)]);
      ra = rb; rb = rc; rc = rd;
    }
  }
  V3 e0 = mkv3(0,0,0), e1 = mkv3(0,0,0);
  if (z0) {
    float x00 = x0[((size_t)b*3 + 0)*COUT + o];
    float x01 = x0[((size_t)b*3 + 1)*COUT + o];
    float x02 = x0[((size_t)b*3 + 2)*COUT + o];
    float first = bv0r + a2*x00 + a1*x01 + a0*x02;
    e0 = mkv3(first, x02, x01);
    e1 = mkv3(bv1r, bv1r, x02);
    V3 q0 = e0, q1 = e1;
#pragma unroll
    for (int k = 0; k < 6; ++k) q0 = aappf(a0,a1,a2, q0);
#pragma unroll
    for (int k = 0; k < 5; ++k) q1 = aappf(a0,a1,a2, q1);
    accE = vadd3(accE, vadd3(q0, q1));
  }
  s_lf[c*8 + o] = accE;
  __syncthreads();

  // ---- in-part 5-level tree over 32 chunk leaves ----
  if (j < 128) { int i = j >> 3; s_tr[i*8+o]      = comb(a0,a1,a2, s_lf[(2*i)*8+o],    s_lf[(2*i+1)*8+o]); }
  __syncthreads();
  if (j < 64)  { int i = j >> 3; s_tr[(16+i)*8+o] = comb(a0,a1,a2, s_tr[(2*i)*8+o],    s_tr[(2*i+1)*8+o]); }
  __syncthreads();
  if (j < 32)  { int i = j >> 3; s_tr[(24+i)*8+o] = comb(a0,a1,a2, s_tr[(16+2*i)*8+o], s_tr[(16+2*i+1)*8+o]); }
  __syncthreads();
  if (j < 16)  { int i = j >> 3; s_tr[(28+i)*8+o] = comb(a0,a1,a2, s_tr[(24+2*i)*8+o], s_tr[(24+2*i+1)*8+o]); }
  __syncthreads();
  if (j < 8) {
    V3 rt = comb(a0,a1,a2, s_tr[28*8+o], s_tr[29*8+o]);
    float* wp = ws + ((size_t)(b*NPART2 + p)*8 + o)*3;
    __hip_atomic_store(wp + 0, rt.x, __ATOMIC_RELAXED, __HIP_MEMORY_SCOPE_AGENT);
    __hip_atomic_store(wp + 1, rt.y, __ATOMIC_RELAXED, __HIP_MEMORY_SCOPE_AGENT);
    __hip_atomic_store(wp + 2, rt.z, __ATOMIC_RELAXED, __HIP_MEMORY_SCOPE_AGENT);
  }

  // ---- device-scope grid barrier (all 512 blocks co-resident) ----
  __syncthreads();                       // drains vmem: root stores issued
  if (j == 0) {
    __threadfence();                     // release
    atomicAdd(bar, 1u);
    while (__hip_atomic_load(bar, __ATOMIC_ACQUIRE, __HIP_MEMORY_SCOPE_AGENT)
           < (unsigned)GRID2) {
      __builtin_amdgcn_s_sleep(2);
    }
  }
  __syncthreads();
  __threadfence();                       // acquire side

  // ---- mini-tree over the 8 part roots of batch b ----
  if (j < 64) {
    int pp = j >> 3;
    const float* wp = ws + ((size_t)(b*NPART2 + pp)*8 + o)*3;
    float rx = __hip_atomic_load(wp + 0, __ATOMIC_RELAXED, __HIP_MEMORY_SCOPE_AGENT);
    float ry = __hip_atomic_load(wp + 1, __ATOMIC_RELAXED, __HIP_MEMORY_SCOPE_AGENT);
    float rz = __hip_atomic_load(wp + 2, __ATOMIC_RELAXED, __HIP_MEMORY_SCOPE_AGENT);
    s_mt[pp*8 + o] = mkv3(rx, ry, rz);
  }
  __syncthreads();
  if (j < 32) { int i = j >> 3; s_mt[(8+i)*8+o]  = comb(a0,a1,a2, s_mt[(2*i)*8+o],   s_mt[(2*i+1)*8+o]); }
  __syncthreads();
  if (j < 16) { int i = j >> 3; s_mt[(12+i)*8+o] = comb(a0,a1,a2, s_mt[(8+2*i)*8+o], s_mt[(8+2*i+1)*8+o]); }
  __syncthreads();
  if (j < 8)  {                 s_mt[14*8+o]     = comb(a0,a1,a2, s_mt[12*8+o],      s_mt[13*8+o]); }
  __syncthreads();

  // ---- sigma = rho(t0 - 1): Fenwick fold, MSB->LSB over (p bits, c bits) ----
  V3 sig = mkv3(0,0,0);
  if ((p >> 2) & 1) sig = comb(a0,a1,a2, sig, s_mt[(12 + (p>>2) - 1)*8 + o]);
  if ((p >> 1) & 1) sig = comb(a0,a1,a2, sig, s_mt[(8  + (p>>1) - 1)*8 + o]);
  if (p & 1)        sig = comb(a0,a1,a2, sig, s_mt[(p - 1)*8 + o]);
  if ((c >> 4) & 1) sig = comb(a0,a1,a2, sig, s_tr[(28 + (c>>4) - 1)*8 + o]);
  if ((c >> 3) & 1) sig = comb(a0,a1,a2, sig, s_tr[(24 + (c>>3) - 1)*8 + o]);
  if ((c >> 2) & 1) sig = comb(a0,a1,a2, sig, s_tr[(16 + (c>>2) - 1)*8 + o]);
  if ((c >> 1) & 1) sig = comb(a0,a1,a2, sig, s_tr[((c>>1) - 1)*8 + o]);
  if (c & 1)        sig = comb(a0,a1,a2, sig, s_lf[(c - 1)*8 + o]);

  // ---- tau = rho(end of part p): fold over q = p+1 parts ----
  V3 tau;
  {
    int q = p + 1;
    if (q == 8) tau = s_mt[14*8+o];
    else {
      tau = mkv3(0,0,0);
      if ((q >> 2) & 1) tau = comb(a0,a1,a2, tau, s_mt[(12 + (q>>2) - 1)*8 + o]);
      if ((q >> 1) & 1) tau = comb(a0,a1,a2, tau, s_mt[(8  + (q>>1) - 1)*8 + o]);
      if (q & 1)        tau = comb(a0,a1,a2, tau, s_mt[(q - 1)*8 + o]);
    }
  }

  // stage sigma (position c*64 - 1) and tau (position 2047) into bv[63] slots
  // (bv[63] is only consumed by the leaf fold, already done; slots disjoint
  //  from the scan's reads r<=62, so no barrier needed before these writes)
  if (c >= 1) s_bv[(c - 1)*BVS + 63*8 + o] = sig.x;
  if (c == NCHK2 - 1) s_bv[(NCHK2 - 1)*BVS + 63*8 + o] = tau.x;

  // ---- local binary-counter scan: positions c*64 + r, r = 0..62, in-place ----
  {
    V3 st[6];
#pragma unroll
    for (int r = 0; r < CHT2 - 1; ++r) {
      float bvr = bvp[r*8];
      V3 v = mkv3(bvr, bvr, bvr);
      if (z0) { if (r == 0) v = e0; if (r == 1) v = e1; }
      if (r & 1)          v = comb(a0,a1,a2, st[0], v);
      if ((r & 3) == 3)   v = comb(a0,a1,a2, st[1], v);
      if ((r & 7) == 7)   v = comb(a0,a1,a2, st[2], v);
      if ((r & 15) == 15) v = comb(a0,a1,a2, st[3], v);
      if ((r & 31) == 31) v = comb(a0,a1,a2, st[4], v);
      st[__popc(r ^ (r + 1)) - 1] = v;   // constant under full unroll
      const int i = r + 1;
      V3 acc = sig;
      if (i & 32) acc = comb(a0,a1,a2, acc, st[5]);
      if (i & 16) acc = comb(a0,a1,a2, acc, st[4]);
      if (i & 8)  acc = comb(a0,a1,a2, acc, st[3]);
      if (i & 4)  acc = comb(a0,a1,a2, acc, st[2]);
      if (i & 2)  acc = comb(a0,a1,a2, acc, st[1]);
      if (i & 1)  acc = comb(a0,a1,a2, acc, st[0]);
      bvp[r*8] = acc.x;
    }
  }
  __syncthreads();

  // ---- coalesced copy-out: 16 iters x 256 threads x float4 ----
  float* og = out + ((size_t)b * T_SZ + (size_t)p * PART2_T) * COUT;
#pragma unroll
  for (int it = 0; it < 16; ++it) {
    int f = (it * 256 + j) * 4;
    float4 v = *(const float4*)&s_bv[(f >> 9) * BVS + (f & 511)];
    *(float4*)&og[f] = v;
  }
}

extern "C" void kernel_launch(void* const* d_in, const int* in_sizes, int n_in,
                              void* d_out, int out_size, void* d_ws, size_t ws_size,
                              hipStream_t stream) {
  const float* u  = (const float*)d_in[0];
  const float* x0 = (const float*)d_in[1];
  const float* ac = (const float*)d_in[2];
  const float* bc = (const float*)d_in[3];
  float* outp = (float*)d_out;
  float* wsp  = (float*)d_ws;
  (void)in_sizes; (void)n_in; (void)out_size;

  // One-time host-side co-residency check (pure host queries; capture-safe).
  static int fused_ok = -1;
  if (fused_ok < 0) {
    int nb = 0, ncu = 0, dev = 0;
    hipGetDevice(&dev);
    hipDeviceProp_t prop;
    if (hipGetDeviceProperties(&prop, dev) == hipSuccess) ncu = prop.multiProcessorCount;
    if (hipOccupancyMaxActiveBlocksPerMultiprocessor(&nb, ldtf_fused512, 256, 0) != hipSuccess) nb = 0;
    fused_ok = (nb > 0 && ncu > 0 && (long)nb * ncu >= GRID2 &&
                ws_size >= (size_t)BAR_OFFSET_BYTES + 16) ? 1 : 0;
  }

  if (fused_ok == 1) {
    unsigned int* bar = (unsigned int*)((char*)d_ws + BAR_OFFSET_BYTES);
    hipMemsetAsync(bar, 0, sizeof(unsigned int), stream);   // ws is poisoned each iter
    ldtf_fused512<<<dim3(GRID2), dim3(256), 0, stream>>>(u, x0, ac, bc, outp, wsp, bar);
  } else {
    ldtf_p1<<<dim3(64 * NPART), dim3(256), 0, stream>>>(u, x0, ac, bc, wsp);
    ldtf_p2<<<dim3(64 * NPART), dim3(256), 0, stream>>>(u, x0, ac, bc, outp, wsp);
  }
}